// Round 8
// baseline (660.029 us; speedup 1.0000x reference)
//
#include <hip/hip_runtime.h>
#include <hip/hip_bf16.h>

#define IN_D 128
#define BN_EPS 1e-5f

// ---------------- CSR build ----------------
// edge_index staged as int32 (harness integer rule). row0 = src[E], row1 = dst[E].

__global__ void k_hist(const int* __restrict__ ei, int* __restrict__ deg, int E, int n) {
    int e = blockIdx.x * 256 + threadIdx.x;
    if (e < E) {
        int dst = ei[E + e];
        if (dst >= 0 && dst < n) atomicAdd(&deg[dst], 1);
    }
}

__global__ void k_block_sum(const int* __restrict__ deg, int* __restrict__ bsum, int n) {
    __shared__ int sdata[256];
    int i = blockIdx.x * 256 + threadIdx.x;
    int v = (i < n) ? deg[i] : 0;
    sdata[threadIdx.x] = v;
    __syncthreads();
    for (int s = 128; s > 0; s >>= 1) {
        if (threadIdx.x < s) sdata[threadIdx.x] += sdata[threadIdx.x + s];
        __syncthreads();
    }
    if (threadIdx.x == 0) bsum[blockIdx.x] = sdata[0];
}

__global__ void k_scan_bsum(int* __restrict__ bsum, int nb) {
    __shared__ int s[256];
    int t = threadIdx.x;
    int v = (t < nb) ? bsum[t] : 0;
    s[t] = v;
    __syncthreads();
    for (int off = 1; off < 256; off <<= 1) {
        int u = (t >= off) ? s[t - off] : 0;
        __syncthreads();
        s[t] += u;
        __syncthreads();
    }
    if (t < nb) bsum[t] = s[t] - v;  // exclusive
}

__global__ void k_scan_deg(const int* __restrict__ deg, const int* __restrict__ boff,
                           int* __restrict__ rowptr, int* __restrict__ cursor,
                           float* __restrict__ invcnt, int n) {
    __shared__ int s[256];
    int t = threadIdx.x;
    int i = blockIdx.x * 256 + t;
    int v = (i < n) ? deg[i] : 0;
    s[t] = v;
    __syncthreads();
    for (int off = 1; off < 256; off <<= 1) {
        int u = (t >= off) ? s[t - off] : 0;
        __syncthreads();
        s[t] += u;
        __syncthreads();
    }
    int incl = s[t];
    int excl = incl - v;
    int base = boff[blockIdx.x];
    if (i < n) {
        rowptr[i] = base + excl;
        cursor[i] = base + excl;
        invcnt[i] = 1.0f / (float)(v < 1 ? 1 : v);
        if (i == n - 1) rowptr[n] = base + incl;
    }
}

// csr entry packed: .x = src node, .y = edge weight bits
__global__ void k_fill(const int* __restrict__ ei, const float* __restrict__ ew,
                       int* __restrict__ cursor, int2* __restrict__ csr, int E, int n) {
    int e = blockIdx.x * 256 + threadIdx.x;
    if (e < E) {
        int dst = ei[E + e];
        int src = ei[e];
        if (dst < 0 || dst >= n) return;
        if (src < 0) src = 0;
        if (src >= n) src = n - 1;
        int slot = atomicAdd(&cursor[dst], 1);
        int2 p;
        p.x = src;
        p.y = __float_as_int(ew[e]);
        csr[slot] = p;
    }
}

// ---------------- aggregation: mean_i = (1/cnt) * sum_j w_ij * x_j ----------------
// UNCHANGED from round 6 (needs counters before touching; will be top-5 next round).
__global__ void k_agg(const float* __restrict__ X, const int* __restrict__ rowptr,
                      const int2* __restrict__ csr, const float* __restrict__ invcnt,
                      float* __restrict__ M, int n) {
    int wid = (blockIdx.x * blockDim.x + threadIdx.x) >> 6;
    int lane = threadIdx.x & 63;
    if (wid >= n) return;
    int beg = __builtin_amdgcn_readfirstlane(rowptr[wid]);
    int end = __builtin_amdgcn_readfirstlane(rowptr[wid + 1]);
    const float2* X2 = (const float2*)X;
    float ax = 0.f, ay = 0.f;
    int k = beg;
    for (; k + 4 <= end; k += 4) {
        int2 e0 = csr[k], e1 = csr[k + 1], e2 = csr[k + 2], e3 = csr[k + 3];
        float2 v0 = X2[(size_t)e0.x * 64 + lane];
        float2 v1 = X2[(size_t)e1.x * 64 + lane];
        float2 v2 = X2[(size_t)e2.x * 64 + lane];
        float2 v3 = X2[(size_t)e3.x * 64 + lane];
        float w0 = __int_as_float(e0.y), w1 = __int_as_float(e1.y);
        float w2 = __int_as_float(e2.y), w3 = __int_as_float(e3.y);
        ax += w0 * v0.x + w1 * v1.x + w2 * v2.x + w3 * v3.x;
        ay += w0 * v0.y + w1 * v1.y + w2 * v2.y + w3 * v3.y;
    }
    for (; k < end; ++k) {
        int2 e = csr[k];
        float w = __int_as_float(e.y);
        float2 v = X2[(size_t)e.x * 64 + lane];
        ax += w * v.x;
        ay += w * v.y;
    }
    float ic = invcnt[wid];
    float2 m;
    m.x = ax * ic;
    m.y = ay * ic;
    ((float2*)M)[(size_t)wid * 64 + lane] = m;
}

// ---------------- GEMM v3: register-pipelined W (T14 async split) ----------------
// out[i][j] = sum_k M[i][k]*Wl[j][k] + b[j] + sum_k X[i][k]*Wr[j][k]
// 256 thr, 32 nodes/block. Wave wv owns nodes wv*8..+7; lane owns col lane (+64).
// Per stage: [bar] ds_write regW->sW  [bar]  issue prefetch(st+1)  compute(st).
// vmcnt wait for the prefetch lands at NEXT stage's ds_write, after ~1K cyc of FMA.
template <int D_OUT, int BN_FLAG>
__global__ __launch_bounds__(256) void k_gemm3(
    const float* __restrict__ M, const float* __restrict__ X,
    const float* __restrict__ Wl, const float* __restrict__ bias,
    const float* __restrict__ Wr,
    const float* __restrict__ bng, const float* __restrict__ bnb,
    const float* __restrict__ bnm, const float* __restrict__ bnv,
    float* __restrict__ Out, int n) {
    constexpr int NJ = D_OUT / 64;
    constexpr int NW = D_OUT / 32;       // float4 of W per thread per 32-k chunk
    __shared__ float sM[32 * 128];       // [node][k] — wave-uniform broadcast reads
    __shared__ float sX[32 * 128];
    __shared__ float sW[D_OUT * 36];     // [j][36] 32-k chunk (16B-aligned, bank-even)

    int t = threadIdx.x;
    int wv = t >> 6;
    int lane = t & 63;
    int node0 = blockIdx.x * 32;

    // thread's slice of a W chunk: element r -> row j, k-quad k4 (within chunk)
    // idx = r*256+t ; j = idx>>3 ; k4 = idx&7
    float4 wreg[NW];
    {
        const float4* W4 = (const float4*)Wl;  // stage 0 chunk: Wl, kc4=0
#pragma unroll
        for (int r = 0; r < NW; ++r) {
            int idx = r * 256 + t;
            wreg[r] = W4[(size_t)(idx >> 3) * 32 + (idx & 7)];
        }
    }

    // stage M/X tiles: 32x128 floats = 1024 float4 / 256 threads = 4 each
    {
        const float4* M4 = (const float4*)(M + (size_t)node0 * 128);
        const float4* X4 = (const float4*)(X + (size_t)node0 * 128);
        float4* sM4 = (float4*)sM;
        float4* sX4 = (float4*)sX;
        float4 z = make_float4(0.f, 0.f, 0.f, 0.f);
#pragma unroll
        for (int r = 0; r < 4; ++r) {
            int idx = r * 256 + t;
            int row = idx >> 5;
            if (node0 + row < n) {
                sM4[idx] = M4[idx];
                sX4[idx] = X4[idx];
            } else {
                sM4[idx] = z;
                sX4[idx] = z;
            }
        }
    }

    float acc[8][NJ];
#pragma unroll
    for (int i = 0; i < 8; ++i)
#pragma unroll
        for (int jj = 0; jj < NJ; ++jj) acc[i][jj] = 0.f;

    // 8 stages: 0-3 = Wl chunks vs sM, 4-7 = Wr chunks vs sX
#pragma unroll 1
    for (int st = 0; st < 8; ++st) {
        __syncthreads();  // previous stage done reading sW; sA staged (st=0)
        // commit prefetched chunk st to LDS (implicit vmcnt wait here)
#pragma unroll
        for (int r = 0; r < NW; ++r) {
            int idx = r * 256 + t;
            *(float4*)&sW[(idx >> 3) * 36 + (idx & 7) * 4] = wreg[r];
        }
        __syncthreads();
        // issue prefetch of chunk st+1 (no wait — overlaps compute below)
        if (st < 7) {
            const float4* W4n = (const float4*)((st + 1 < 4) ? Wl : Wr);
            int kc4n = ((st + 1) & 3) * 8;
#pragma unroll
            for (int r = 0; r < NW; ++r) {
                int idx = r * 256 + t;
                wreg[r] = W4n[(size_t)(idx >> 3) * 32 + kc4n + (idx & 7)];
            }
        }
        // compute chunk st: 32 k values
        const float* sA = (st < 4) ? sM : sX;
        int kc = (st & 3) * 32;
#pragma unroll
        for (int k4 = 0; k4 < 8; ++k4) {
            float4 w[NJ];
#pragma unroll
            for (int jj = 0; jj < NJ; ++jj)
                w[jj] = *(const float4*)&sW[(lane + jj * 64) * 36 + k4 * 4];
#pragma unroll
            for (int i = 0; i < 8; ++i) {
                float4 a = *(const float4*)&sA[(wv * 8 + i) * 128 + kc + k4 * 4];
#pragma unroll
                for (int jj = 0; jj < NJ; ++jj) {
                    acc[i][jj] += a.x * w[jj].x + a.y * w[jj].y + a.z * w[jj].z +
                                  a.w * w[jj].w;
                }
            }
        }
    }

    // epilogue
    if constexpr (BN_FLAG) {
#pragma unroll
        for (int jj = 0; jj < NJ; ++jj) {
            int j = lane + jj * 64;
            float bj = bias[j];
            float g = bng[j], bb = bnb[j], mm = bnm[j];
            float iv = rsqrtf(bnv[j] + BN_EPS);
#pragma unroll
            for (int i = 0; i < 8; ++i) {
                int node = node0 + wv * 8 + i;
                float h = acc[i][jj] + bj;
                h = (h - mm) * (g * iv) + bb;
                h = h >= 0.f ? h : 0.1f * h;
                if (node < n) Out[(size_t)node * D_OUT + j] = h;
            }
        }
    } else {
        // D_OUT == 64: row L2-normalize within the wave
        float bj = bias[lane];
#pragma unroll
        for (int i = 0; i < 8; ++i) {
            float h = acc[i][0] + bj;
            float ss = h * h;
#pragma unroll
            for (int o = 32; o >= 1; o >>= 1) ss += __shfl_xor(ss, o, 64);
            float sc = 1.0f / fmaxf(sqrtf(ss), 1e-12f);
            int node = node0 + wv * 8 + i;
            if (node < n) Out[(size_t)node * 64 + lane] = h * sc;
        }
    }
}

// ---------------- launch ----------------

extern "C" void kernel_launch(void* const* d_in, const int* in_sizes, int n_in,
                              void* d_out, int out_size, void* d_ws, size_t ws_size,
                              hipStream_t stream) {
    const float* x = (const float*)d_in[0];
    const int* ei = (const int*)d_in[1];  // int32 staging
    const float* ew = (const float*)d_in[2];
    const float* W1l = (const float*)d_in[3];
    const float* b1 = (const float*)d_in[4];
    const float* W1r = (const float*)d_in[5];
    const float* W2l = (const float*)d_in[6];
    const float* b2 = (const float*)d_in[7];
    const float* W2r = (const float*)d_in[8];
    const float* W3l = (const float*)d_in[9];
    const float* b3 = (const float*)d_in[10];
    const float* W3r = (const float*)d_in[11];
    const float* bn1_g = (const float*)d_in[12];
    const float* bn1_b = (const float*)d_in[13];
    const float* bn1_m = (const float*)d_in[14];
    const float* bn1_v = (const float*)d_in[15];
    const float* bn2_g = (const float*)d_in[16];
    const float* bn2_b = (const float*)d_in[17];
    const float* bn2_m = (const float*)d_in[18];
    const float* bn2_v = (const float*)d_in[19];

    const int N = in_sizes[0] / IN_D;  // 50000
    const int E = in_sizes[2];         // 800000
    float* out = (float*)d_out;

    char* p = (char*)d_ws;
    auto alloc = [&](size_t bytes) -> void* {
        void* r = (void*)p;
        p += (bytes + 255) & ~(size_t)255;
        return r;
    };
    int* deg = (int*)alloc((size_t)N * 4);
    int* rowptr = (int*)alloc((size_t)(N + 1) * 4);
    int* cursor = (int*)alloc((size_t)N * 4);
    float* invcnt = (float*)alloc((size_t)N * 4);
    int* bsum = (int*)alloc(256 * 4);
    int2* csr = (int2*)alloc((size_t)E * 8);
    float* Mbuf = (float*)alloc((size_t)N * 128 * 4);
    float* H1 = (float*)alloc((size_t)N * 128 * 4);
    float* H2 = (float*)alloc((size_t)N * 128 * 4);

    const int NB = (N + 255) / 256;
    const int EB = (E + 255) / 256;
    const int AGG_B = (N + 3) / 4;        // 4 waves (nodes) per 256-thread block
    const int GEMM_B = (N + 31) / 32;     // 32 nodes per 256-thread block

    // --- CSR build ---
    hipMemsetAsync(deg, 0, (size_t)N * 4, stream);
    k_hist<<<EB, 256, 0, stream>>>(ei, deg, E, N);
    k_block_sum<<<NB, 256, 0, stream>>>(deg, bsum, N);
    k_scan_bsum<<<1, 256, 0, stream>>>(bsum, NB);
    k_scan_deg<<<NB, 256, 0, stream>>>(deg, bsum, rowptr, cursor, invcnt, N);
    k_fill<<<EB, 256, 0, stream>>>(ei, ew, cursor, csr, E, N);

    // --- layer 1 ---
    k_agg<<<AGG_B, 256, 0, stream>>>(x, rowptr, csr, invcnt, Mbuf, N);
    k_gemm3<128, 1><<<GEMM_B, 256, 0, stream>>>(Mbuf, x, W1l, b1, W1r, bn1_g, bn1_b,
                                                bn1_m, bn1_v, H1, N);
    // --- layer 2 ---
    k_agg<<<AGG_B, 256, 0, stream>>>(H1, rowptr, csr, invcnt, Mbuf, N);
    k_gemm3<128, 1><<<GEMM_B, 256, 0, stream>>>(Mbuf, H1, W2l, b2, W2r, bn2_g, bn2_b,
                                                bn2_m, bn2_v, H2, N);
    // --- layer 3 (+ fused L2 normalize) ---
    k_agg<<<AGG_B, 256, 0, stream>>>(H2, rowptr, csr, invcnt, Mbuf, N);
    k_gemm3<64, 0><<<GEMM_B, 256, 0, stream>>>(Mbuf, H2, W3l, b3, W3r, nullptr, nullptr,
                                               nullptr, nullptr, out, N);
}

// Round 9
// 586.757 us; speedup vs baseline: 1.1249x; 1.1249x over previous
//
#include <hip/hip_runtime.h>
#include <hip/hip_bf16.h>

#define IN_D 128
#define BN_EPS 1e-5f

// ---------------- CSR build ----------------
// edge_index staged as int32 (harness integer rule). row0 = src[E], row1 = dst[E].

__global__ void k_hist(const int* __restrict__ ei, int* __restrict__ deg, int E, int n) {
    int e = blockIdx.x * 256 + threadIdx.x;
    if (e < E) {
        int dst = ei[E + e];
        if (dst >= 0 && dst < n) atomicAdd(&deg[dst], 1);
    }
}

__global__ void k_block_sum(const int* __restrict__ deg, int* __restrict__ bsum, int n) {
    __shared__ int sdata[256];
    int i = blockIdx.x * 256 + threadIdx.x;
    int v = (i < n) ? deg[i] : 0;
    sdata[threadIdx.x] = v;
    __syncthreads();
    for (int s = 128; s > 0; s >>= 1) {
        if (threadIdx.x < s) sdata[threadIdx.x] += sdata[threadIdx.x + s];
        __syncthreads();
    }
    if (threadIdx.x == 0) bsum[blockIdx.x] = sdata[0];
}

__global__ void k_scan_bsum(int* __restrict__ bsum, int nb) {
    __shared__ int s[256];
    int t = threadIdx.x;
    int v = (t < nb) ? bsum[t] : 0;
    s[t] = v;
    __syncthreads();
    for (int off = 1; off < 256; off <<= 1) {
        int u = (t >= off) ? s[t - off] : 0;
        __syncthreads();
        s[t] += u;
        __syncthreads();
    }
    if (t < nb) bsum[t] = s[t] - v;  // exclusive
}

__global__ void k_scan_deg(const int* __restrict__ deg, const int* __restrict__ boff,
                           int* __restrict__ rowptr, int* __restrict__ cursor,
                           float* __restrict__ invcnt, int n) {
    __shared__ int s[256];
    int t = threadIdx.x;
    int i = blockIdx.x * 256 + t;
    int v = (i < n) ? deg[i] : 0;
    s[t] = v;
    __syncthreads();
    for (int off = 1; off < 256; off <<= 1) {
        int u = (t >= off) ? s[t - off] : 0;
        __syncthreads();
        s[t] += u;
        __syncthreads();
    }
    int incl = s[t];
    int excl = incl - v;
    int base = boff[blockIdx.x];
    if (i < n) {
        rowptr[i] = base + excl;
        cursor[i] = base + excl;
        invcnt[i] = 1.0f / (float)(v < 1 ? 1 : v);
        if (i == n - 1) rowptr[n] = base + incl;
    }
}

// csr entry packed: .x = src node, .y = edge weight bits
__global__ void k_fill(const int* __restrict__ ei, const float* __restrict__ ew,
                       int* __restrict__ cursor, int2* __restrict__ csr, int E, int n) {
    int e = blockIdx.x * 256 + threadIdx.x;
    if (e < E) {
        int dst = ei[E + e];
        int src = ei[e];
        if (dst < 0 || dst >= n) return;
        if (src < 0) src = 0;
        if (src >= n) src = n - 1;
        int slot = atomicAdd(&cursor[dst], 1);
        int2 p;
        p.x = src;
        p.y = __float_as_int(ew[e]);
        csr[slot] = p;
    }
}

// ---------------- fused weight transpose: W[DO][128] -> WT[128][DO] ----------------
// segments: 4x (128x128) + 2x (64x128). 320 blocks x 256 thr.
__global__ void k_transp(const float* __restrict__ W1l, const float* __restrict__ W1r,
                         const float* __restrict__ W2l, const float* __restrict__ W2r,
                         const float* __restrict__ W3l, const float* __restrict__ W3r,
                         float* __restrict__ T1l, float* __restrict__ T1r,
                         float* __restrict__ T2l, float* __restrict__ T2r,
                         float* __restrict__ T3l, float* __restrict__ T3r) {
    int b = blockIdx.x;
    const float* src;
    float* dst;
    int DO, base;
    if (b < 64)       { src = W1l; dst = T1l; DO = 128; base = b; }
    else if (b < 128) { src = W1r; dst = T1r; DO = 128; base = b - 64; }
    else if (b < 192) { src = W2l; dst = T2l; DO = 128; base = b - 128; }
    else if (b < 256) { src = W2r; dst = T2r; DO = 128; base = b - 192; }
    else if (b < 288) { src = W3l; dst = T3l; DO = 64;  base = b - 256; }
    else              { src = W3r; dst = T3r; DO = 64;  base = b - 288; }
    int eid = base * 256 + threadIdx.x;   // 0 .. DO*128-1
    int k = eid & 127;
    int j = eid >> 7;
    dst[k * DO + j] = src[j * 128 + k];   // coalesced read, strided write (tiny)
}

// ---------------- aggregation: mean_i = (1/cnt) * sum_j w_ij * x_j ----------------
// UNCHANGED (no counters yet; expected in top-5 next round).
__global__ void k_agg(const float* __restrict__ X, const int* __restrict__ rowptr,
                      const int2* __restrict__ csr, const float* __restrict__ invcnt,
                      float* __restrict__ M, int n) {
    int wid = (blockIdx.x * blockDim.x + threadIdx.x) >> 6;
    int lane = threadIdx.x & 63;
    if (wid >= n) return;
    int beg = __builtin_amdgcn_readfirstlane(rowptr[wid]);
    int end = __builtin_amdgcn_readfirstlane(rowptr[wid + 1]);
    const float2* X2 = (const float2*)X;
    float ax = 0.f, ay = 0.f;
    int k = beg;
    for (; k + 4 <= end; k += 4) {
        int2 e0 = csr[k], e1 = csr[k + 1], e2 = csr[k + 2], e3 = csr[k + 3];
        float2 v0 = X2[(size_t)e0.x * 64 + lane];
        float2 v1 = X2[(size_t)e1.x * 64 + lane];
        float2 v2 = X2[(size_t)e2.x * 64 + lane];
        float2 v3 = X2[(size_t)e3.x * 64 + lane];
        float w0 = __int_as_float(e0.y), w1 = __int_as_float(e1.y);
        float w2 = __int_as_float(e2.y), w3 = __int_as_float(e3.y);
        ax += w0 * v0.x + w1 * v1.x + w2 * v2.x + w3 * v3.x;
        ay += w0 * v0.y + w1 * v1.y + w2 * v2.y + w3 * v3.y;
    }
    for (; k < end; ++k) {
        int2 e = csr[k];
        float w = __int_as_float(e.y);
        float2 v = X2[(size_t)e.x * 64 + lane];
        ax += w * v.x;
        ay += w * v.y;
    }
    float ic = invcnt[wid];
    float2 m;
    m.x = ax * ic;
    m.y = ay * ic;
    ((float2*)M)[(size_t)wid * 64 + lane] = m;
}

// ---------------- GEMM v4: lane=node, scalar-pipe W, swizzled LDS A ----------------
// out[i][j] = sum_k M[i][k]*WTl[k][j] + b[j] + sum_k X[i][k]*WTr[k][j]
// 256 thr, 64 nodes/block; lane owns node (node0+lane); wave wv owns cols
// j = jb..jb+JW-1 (jb = wv*JW, readfirstlane-rooted -> W address is scalar).
// A staged once per phase in LDS with 4B XOR swizzle (k ^ (lane&31)):
// per-k read = 32 distinct banks, 2 lanes/bank (free). 3 barriers total.
template <int DO, int BN_FLAG>
__global__ __launch_bounds__(256) void k_gemm4(
    const float* __restrict__ M, const float* __restrict__ X,
    const float* __restrict__ WTl, const float* __restrict__ bias,
    const float* __restrict__ WTr,
    const float* __restrict__ bng, const float* __restrict__ bnb,
    const float* __restrict__ bnm, const float* __restrict__ bnv,
    float* __restrict__ Out, int n) {
    constexpr int JW = DO / 4;          // cols per wave: 32 (DO=128) or 16 (DO=64)
    __shared__ float sA[64 * 128];      // 32 KB, reused for M then X
    __shared__ float ssbuf[4][64];      // layer-3 L2-norm partials

    int t = threadIdx.x;
    int lane = t & 63;
    int wv = t >> 6;
    int jb = __builtin_amdgcn_readfirstlane(wv * JW);
    int node0 = blockIdx.x * 64;
    int node = node0 + lane;
    int sx = lane & 31;
    int arow = lane * 128;

    float acc[JW];
#pragma unroll
    for (int jj = 0; jj < JW; ++jj) acc[jj] = 0.f;

    // ---------------- phase 1: A = M, W = WTl ; phase 2: A = X, W = WTr -------------
#pragma unroll 1
    for (int ph = 0; ph < 2; ++ph) {
        const float* src = (ph == 0) ? M : X;
        const float* wt = (ph == 0) ? WTl : WTr;
        if (ph == 1) __syncthreads();  // all waves done reading sA(M)
        // stage 64x128 tile, swizzled
        {
            const float4* S4 = (const float4*)(src + (size_t)node0 * 128);
            float4 z = make_float4(0.f, 0.f, 0.f, 0.f);
#pragma unroll
            for (int r = 0; r < 8; ++r) {
                int idx = r * 256 + t;      // 0..2047 float4s
                int nd = idx >> 5;          // node in tile
                int k0 = (idx & 31) * 4;
                float4 f = (node0 + nd < n) ? S4[idx] : z;
                int swz = nd & 31;
                int base = nd * 128;
                sA[base + ((k0 + 0) ^ swz)] = f.x;
                sA[base + ((k0 + 1) ^ swz)] = f.y;
                sA[base + ((k0 + 2) ^ swz)] = f.z;
                sA[base + ((k0 + 3) ^ swz)] = f.w;
            }
        }
        __syncthreads();
        // compute: k-loop, W rows via scalar loads (wave-uniform addr)
#pragma unroll 1
        for (int k = 0; k < 128; k += 4) {
            float a0 = sA[arow + ((k + 0) ^ sx)];
            float a1 = sA[arow + ((k + 1) ^ sx)];
            float a2 = sA[arow + ((k + 2) ^ sx)];
            float a3 = sA[arow + ((k + 3) ^ sx)];
            const float* w0 = wt + (size_t)(k + 0) * DO + jb;
            const float* w1 = wt + (size_t)(k + 1) * DO + jb;
            const float* w2 = wt + (size_t)(k + 2) * DO + jb;
            const float* w3 = wt + (size_t)(k + 3) * DO + jb;
#pragma unroll
            for (int jj = 0; jj < JW; ++jj) acc[jj] += a0 * w0[jj];
#pragma unroll
            for (int jj = 0; jj < JW; ++jj) acc[jj] += a1 * w1[jj];
#pragma unroll
            for (int jj = 0; jj < JW; ++jj) acc[jj] += a2 * w2[jj];
#pragma unroll
            for (int jj = 0; jj < JW; ++jj) acc[jj] += a3 * w3[jj];
        }
    }

    // ---------------- epilogue ----------------
    if constexpr (BN_FLAG) {
#pragma unroll
        for (int jj = 0; jj < JW; ++jj) {
            int j = jb + jj;
            float h = acc[jj] + bias[j];
            h = (h - bnm[j]) * (bng[j] * rsqrtf(bnv[j] + BN_EPS)) + bnb[j];
            acc[jj] = h >= 0.f ? h : 0.1f * h;
        }
        if (node < n) {
            float4* O4 = (float4*)(Out + (size_t)node * DO + jb);
#pragma unroll
            for (int q = 0; q < JW / 4; ++q)
                O4[q] = make_float4(acc[q * 4], acc[q * 4 + 1], acc[q * 4 + 2],
                                    acc[q * 4 + 3]);
        }
    } else {
        // DO == 64: bias + row-L2-normalize (row spans 4 waves -> LDS partials)
        float ss = 0.f;
#pragma unroll
        for (int jj = 0; jj < JW; ++jj) {
            acc[jj] += bias[jb + jj];
            ss += acc[jj] * acc[jj];
        }
        ssbuf[wv][lane] = ss;
        __syncthreads();
        float tot = ssbuf[0][lane] + ssbuf[1][lane] + ssbuf[2][lane] + ssbuf[3][lane];
        float sc = 1.0f / fmaxf(sqrtf(tot), 1e-12f);
        if (node < n) {
            float4* O4 = (float4*)(Out + (size_t)node * DO + jb);
#pragma unroll
            for (int q = 0; q < JW / 4; ++q)
                O4[q] = make_float4(acc[q * 4] * sc, acc[q * 4 + 1] * sc,
                                    acc[q * 4 + 2] * sc, acc[q * 4 + 3] * sc);
        }
    }
}

// ---------------- launch ----------------

extern "C" void kernel_launch(void* const* d_in, const int* in_sizes, int n_in,
                              void* d_out, int out_size, void* d_ws, size_t ws_size,
                              hipStream_t stream) {
    const float* x = (const float*)d_in[0];
    const int* ei = (const int*)d_in[1];  // int32 staging
    const float* ew = (const float*)d_in[2];
    const float* W1l = (const float*)d_in[3];
    const float* b1 = (const float*)d_in[4];
    const float* W1r = (const float*)d_in[5];
    const float* W2l = (const float*)d_in[6];
    const float* b2 = (const float*)d_in[7];
    const float* W2r = (const float*)d_in[8];
    const float* W3l = (const float*)d_in[9];
    const float* b3 = (const float*)d_in[10];
    const float* W3r = (const float*)d_in[11];
    const float* bn1_g = (const float*)d_in[12];
    const float* bn1_b = (const float*)d_in[13];
    const float* bn1_m = (const float*)d_in[14];
    const float* bn1_v = (const float*)d_in[15];
    const float* bn2_g = (const float*)d_in[16];
    const float* bn2_b = (const float*)d_in[17];
    const float* bn2_m = (const float*)d_in[18];
    const float* bn2_v = (const float*)d_in[19];

    const int N = in_sizes[0] / IN_D;  // 50000
    const int E = in_sizes[2];         // 800000
    float* out = (float*)d_out;

    char* p = (char*)d_ws;
    auto alloc = [&](size_t bytes) -> void* {
        void* r = (void*)p;
        p += (bytes + 255) & ~(size_t)255;
        return r;
    };
    int* deg = (int*)alloc((size_t)N * 4);
    int* rowptr = (int*)alloc((size_t)(N + 1) * 4);
    int* cursor = (int*)alloc((size_t)N * 4);
    float* invcnt = (float*)alloc((size_t)N * 4);
    int* bsum = (int*)alloc(256 * 4);
    int2* csr = (int2*)alloc((size_t)E * 8);
    float* Mbuf = (float*)alloc((size_t)N * 128 * 4);
    float* H1 = (float*)alloc((size_t)N * 128 * 4);
    float* H2 = (float*)alloc((size_t)N * 128 * 4);
    float* T1l = (float*)alloc(128 * 128 * 4);
    float* T1r = (float*)alloc(128 * 128 * 4);
    float* T2l = (float*)alloc(128 * 128 * 4);
    float* T2r = (float*)alloc(128 * 128 * 4);
    float* T3l = (float*)alloc(128 * 64 * 4);
    float* T3r = (float*)alloc(128 * 64 * 4);

    const int NB = (N + 255) / 256;
    const int EB = (E + 255) / 256;
    const int AGG_B = (N + 3) / 4;        // 4 waves (nodes) per 256-thread block
    const int GEMM_B = (N + 63) / 64;     // 64 nodes per 256-thread block

    // --- CSR build + weight transpose ---
    hipMemsetAsync(deg, 0, (size_t)N * 4, stream);
    k_hist<<<EB, 256, 0, stream>>>(ei, deg, E, N);
    k_transp<<<320, 256, 0, stream>>>(W1l, W1r, W2l, W2r, W3l, W3r,
                                      T1l, T1r, T2l, T2r, T3l, T3r);
    k_block_sum<<<NB, 256, 0, stream>>>(deg, bsum, N);
    k_scan_bsum<<<1, 256, 0, stream>>>(bsum, NB);
    k_scan_deg<<<NB, 256, 0, stream>>>(deg, bsum, rowptr, cursor, invcnt, N);
    k_fill<<<EB, 256, 0, stream>>>(ei, ew, cursor, csr, E, N);

    // --- layer 1 ---
    k_agg<<<AGG_B, 256, 0, stream>>>(x, rowptr, csr, invcnt, Mbuf, N);
    k_gemm4<128, 1><<<GEMM_B, 256, 0, stream>>>(Mbuf, x, T1l, b1, T1r, bn1_g, bn1_b,
                                                bn1_m, bn1_v, H1, N);
    // --- layer 2 ---
    k_agg<<<AGG_B, 256, 0, stream>>>(H1, rowptr, csr, invcnt, Mbuf, N);
    k_gemm4<128, 1><<<GEMM_B, 256, 0, stream>>>(Mbuf, H1, T2l, b2, T2r, bn2_g, bn2_b,
                                                bn2_m, bn2_v, H2, N);
    // --- layer 3 (+ fused L2 normalize) ---
    k_agg<<<AGG_B, 256, 0, stream>>>(H2, rowptr, csr, invcnt, Mbuf, N);
    k_gemm4<64, 0><<<GEMM_B, 256, 0, stream>>>(Mbuf, H2, T3l, b3, T3r, nullptr, nullptr,
                                               nullptr, nullptr, out, N);
}

// Round 11
// 341.465 us; speedup vs baseline: 1.9329x; 1.7184x over previous
//
#include <hip/hip_runtime.h>
#include <hip/hip_bf16.h>

#define IN_D 128
#define BN_EPS 1e-5f

typedef short bf8 __attribute__((ext_vector_type(8)));   // 8 bf16 = 4 VGPR (guide §3)
typedef float f32x4 __attribute__((ext_vector_type(4)));

__device__ __forceinline__ ushort f2bf(float f) {        // f32 -> bf16 RNE
    unsigned u = __float_as_uint(f);
    unsigned r = u + 0x7fffu + ((u >> 16) & 1u);
    return (ushort)(r >> 16);
}

// ---------------- CSR build (unchanged since round 6) ----------------

__global__ void k_hist(const int* __restrict__ ei, int* __restrict__ deg, int E, int n) {
    int e = blockIdx.x * 256 + threadIdx.x;
    if (e < E) {
        int dst = ei[E + e];
        if (dst >= 0 && dst < n) atomicAdd(&deg[dst], 1);
    }
}

__global__ void k_block_sum(const int* __restrict__ deg, int* __restrict__ bsum, int n) {
    __shared__ int sdata[256];
    int i = blockIdx.x * 256 + threadIdx.x;
    int v = (i < n) ? deg[i] : 0;
    sdata[threadIdx.x] = v;
    __syncthreads();
    for (int s = 128; s > 0; s >>= 1) {
        if (threadIdx.x < s) sdata[threadIdx.x] += sdata[threadIdx.x + s];
        __syncthreads();
    }
    if (threadIdx.x == 0) bsum[blockIdx.x] = sdata[0];
}

__global__ void k_scan_bsum(int* __restrict__ bsum, int nb) {
    __shared__ int s[256];
    int t = threadIdx.x;
    int v = (t < nb) ? bsum[t] : 0;
    s[t] = v;
    __syncthreads();
    for (int off = 1; off < 256; off <<= 1) {
        int u = (t >= off) ? s[t - off] : 0;
        __syncthreads();
        s[t] += u;
        __syncthreads();
    }
    if (t < nb) bsum[t] = s[t] - v;  // exclusive
}

__global__ void k_scan_deg(const int* __restrict__ deg, const int* __restrict__ boff,
                           int* __restrict__ rowptr, int* __restrict__ cursor,
                           float* __restrict__ invcnt, int n) {
    __shared__ int s[256];
    int t = threadIdx.x;
    int i = blockIdx.x * 256 + t;
    int v = (i < n) ? deg[i] : 0;
    s[t] = v;
    __syncthreads();
    for (int off = 1; off < 256; off <<= 1) {
        int u = (t >= off) ? s[t - off] : 0;
        __syncthreads();
        s[t] += u;
        __syncthreads();
    }
    int incl = s[t];
    int excl = incl - v;
    int base = boff[blockIdx.x];
    if (i < n) {
        rowptr[i] = base + excl;
        cursor[i] = base + excl;
        invcnt[i] = 1.0f / (float)(v < 1 ? 1 : v);
        if (i == n - 1) rowptr[n] = base + incl;
    }
}

__global__ void k_fill(const int* __restrict__ ei, const float* __restrict__ ew,
                       int* __restrict__ cursor, int2* __restrict__ csr, int E, int n) {
    int e = blockIdx.x * 256 + threadIdx.x;
    if (e < E) {
        int dst = ei[E + e];
        int src = ei[e];
        if (dst < 0 || dst >= n) return;
        if (src < 0) src = 0;
        if (src >= n) src = n - 1;
        int slot = atomicAdd(&cursor[dst], 1);
        int2 p;
        p.x = src;
        p.y = __float_as_int(ew[e]);
        csr[slot] = p;
    }
}

// ---------------- x (f32) -> xb (bf16) ----------------
__global__ void k_cvt(const float4* __restrict__ X4, ushort4* __restrict__ Ob, int n4) {
    int i = blockIdx.x * 256 + threadIdx.x;
    if (i < n4) {
        float4 f = X4[i];
        ushort4 o;
        o.x = f2bf(f.x); o.y = f2bf(f.y); o.z = f2bf(f.z); o.w = f2bf(f.w);
        Ob[i] = o;
    }
}

// ---------------- W -> B-fragment-ordered bf16 pack ----------------
// WB[jc][kc][g][j0][e] = bf16( (kc<4 ? Wl : Wr)[jc*16+j0][(kc&3)*32 + g*8 + e] )
// so a lane's B-frag (16x16x32 layout: col=lane&15, k=(lane>>4)*8+e) is one
// contiguous 16B read at ((jc*8+kc)*4+g)*128 + (lane&15)*8.
__global__ void k_prep(const float* __restrict__ W1l, const float* __restrict__ W1r,
                       const float* __restrict__ W2l, const float* __restrict__ W2r,
                       const float* __restrict__ W3l, const float* __restrict__ W3r,
                       ushort* __restrict__ WB1, ushort* __restrict__ WB2,
                       ushort* __restrict__ WB3) {
    int e = blockIdx.x * 256 + threadIdx.x;  // 0..81919
    const float *Wl, *Wr;
    ushort* dst;
    int idx;
    if (e < 32768)      { Wl = W1l; Wr = W1r; dst = WB1; idx = e; }
    else if (e < 65536) { Wl = W2l; Wr = W2r; dst = WB2; idx = e - 32768; }
    else                { Wl = W3l; Wr = W3r; dst = WB3; idx = e - 65536; }
    int ei = idx & 7, j0 = (idx >> 3) & 15, g = (idx >> 7) & 3, kc = (idx >> 9) & 7,
        jc = idx >> 12;
    int ksrc = (kc & 3) * 32 + g * 8 + ei;
    int jsrc = jc * 16 + j0;
    const float* src = (kc < 4) ? Wl : Wr;
    dst[idx] = f2bf(src[jsrc * 128 + ksrc]);
}

// ---------------- aggregation (bf16 in/out): mean_i = (1/cnt) sum w_ij x_j ---------
// one wave per node; lane owns dims 2l,2l+1 packed in one uint (2 bf16). 4x unroll.
__global__ void k_agg(const unsigned* __restrict__ Xb2, const int* __restrict__ rowptr,
                      const int2* __restrict__ csr, const float* __restrict__ invcnt,
                      unsigned* __restrict__ Mb2, int n) {
    int wid = (blockIdx.x * blockDim.x + threadIdx.x) >> 6;
    int lane = threadIdx.x & 63;
    if (wid >= n) return;
    int beg = __builtin_amdgcn_readfirstlane(rowptr[wid]);
    int end = __builtin_amdgcn_readfirstlane(rowptr[wid + 1]);
    float ax = 0.f, ay = 0.f;
    int k = beg;
    for (; k + 4 <= end; k += 4) {
        int2 e0 = csr[k], e1 = csr[k + 1], e2 = csr[k + 2], e3 = csr[k + 3];
        unsigned v0 = Xb2[(size_t)e0.x * 64 + lane];
        unsigned v1 = Xb2[(size_t)e1.x * 64 + lane];
        unsigned v2 = Xb2[(size_t)e2.x * 64 + lane];
        unsigned v3 = Xb2[(size_t)e3.x * 64 + lane];
        float w0 = __int_as_float(e0.y), w1 = __int_as_float(e1.y);
        float w2 = __int_as_float(e2.y), w3 = __int_as_float(e3.y);
        ax += w0 * __uint_as_float(v0 << 16) + w1 * __uint_as_float(v1 << 16) +
              w2 * __uint_as_float(v2 << 16) + w3 * __uint_as_float(v3 << 16);
        ay += w0 * __uint_as_float(v0 & 0xffff0000u) + w1 * __uint_as_float(v1 & 0xffff0000u) +
              w2 * __uint_as_float(v2 & 0xffff0000u) + w3 * __uint_as_float(v3 & 0xffff0000u);
    }
    for (; k < end; ++k) {
        int2 e = csr[k];
        float w = __int_as_float(e.y);
        unsigned v = Xb2[(size_t)e.x * 64 + lane];
        ax += w * __uint_as_float(v << 16);
        ay += w * __uint_as_float(v & 0xffff0000u);
    }
    float ic = invcnt[wid];
    Mb2[(size_t)wid * 64 + lane] =
        (unsigned)f2bf(ax * ic) | ((unsigned)f2bf(ay * ic) << 16);
}

// ---------------- GEMM v5: bf16 MFMA ----------------
// D[node][j] = sum_k A[node][k] * B[k][j],  A = [M | X] (K=256, bf16),
// B[k][j] = (k<128 ? Wl : Wr)[j][k&127]  (pre-packed WB).
// Block: 32 nodes x DO cols, 256 thr (4 waves). Wave wv owns col-frags
// jc = wv*CF..wv*CF+CF-1 (CF = DO/64), both 16-node row-frags.
// A staged in LDS (XOR-swizzled, G4); B-frags read straight from global (L2-hot).
// BN_FLAG=1: BN+leaky -> bf16 H (LDS repack, coalesced store).
// BN_FLAG=0: DO=64, bias + fused row-L2-norm -> f32 out.
template <int DO, int BN_FLAG>
__global__ __launch_bounds__(256) void k_gemm5(
    const ushort* __restrict__ Mb, const ushort* __restrict__ Xb,
    const ushort* __restrict__ WB, const float* __restrict__ bias,
    const float* __restrict__ bng, const float* __restrict__ bnb,
    const float* __restrict__ bnm, const float* __restrict__ bnv,
    void* __restrict__ OutP, int n) {
    constexpr int CF = DO / 64;
    __shared__ ushort sAb[32 * 256];  // 16 KB: [node][k] bf16, XOR-swizzled
    __shared__ float ssrow[32];

    int t = threadIdx.x;
    int wv = t >> 6;
    int lane = t & 63;
    int rowl = lane & 15;
    int g = lane >> 4;
    int node0 = blockIdx.x * 32;

    // ---- stage A = [M | X] tile (32 x 256 bf16), swizzle byte ^= (node&7)<<4 ----
    {
        const uint4* Ms = (const uint4*)(Mb + (size_t)node0 * 128);
        const uint4* Xs = (const uint4*)(Xb + (size_t)node0 * 128);
        uint4 z = make_uint4(0, 0, 0, 0);
#pragma unroll
        for (int it = 0; it < 4; ++it) {
            int idx = it * 256 + t;      // 1024 16B-units
            int nd = idx >> 5;           // node 0..31
            int u = idx & 31;            // 16B unit within 512B row
            bool ok = (node0 + nd) < n;
            uint4 vv = ok ? (u < 16 ? Ms[nd * 16 + u] : Xs[nd * 16 + (u - 16)]) : z;
            int byte = nd * 512 + ((u * 16) ^ ((nd & 7) << 4));
            *(uint4*)((char*)sAb + byte) = vv;
        }
        if (BN_FLAG == 0 && t < 32) ssrow[t] = 0.f;
    }
    __syncthreads();

    // ---- MFMA main loop: K = 256 = 8 kc-steps of 32 ----
    f32x4 acc[2][CF];
#pragma unroll
    for (int nf = 0; nf < 2; ++nf)
#pragma unroll
        for (int cf = 0; cf < CF; ++cf) acc[nf][cf] = (f32x4)0.f;

#pragma unroll
    for (int kc = 0; kc < 8; ++kc) {
        bf8 a[2];
#pragma unroll
        for (int nf = 0; nf < 2; ++nf) {
            int nl = nf * 16 + rowl;  // A-frag: row = lane&15, k = g*8+e
            int byte = nl * 512 + (((kc * 64) + g * 16) ^ ((nl & 7) << 4));
            a[nf] = *(const bf8*)((const char*)sAb + byte);
        }
#pragma unroll
        for (int cf = 0; cf < CF; ++cf) {
            int jc = wv * CF + cf;
            bf8 b = *(const bf8*)(WB + (((jc * 8 + kc) * 4 + g) * 128 + rowl * 8));
#pragma unroll
            for (int nf = 0; nf < 2; ++nf)
                acc[nf][cf] =
                    __builtin_amdgcn_mfma_f32_16x16x32_bf16(a[nf], b, acc[nf][cf], 0, 0, 0);
        }
    }

    // ---- epilogue ----
    if constexpr (BN_FLAG) {
        __syncthreads();               // done reading sAb; reuse as H tile
        ushort* sH = sAb;              // [32][DO] bf16
#pragma unroll
        for (int cf = 0; cf < CF; ++cf) {
            int j = (wv * CF + cf) * 16 + rowl;
            float bj = bias[j];
            float gm = bng[j], bb = bnb[j], mm = bnm[j];
            float iv = rsqrtf(bnv[j] + BN_EPS);
#pragma unroll
            for (int nf = 0; nf < 2; ++nf) {
#pragma unroll
                for (int r = 0; r < 4; ++r) {
                    int nrow = nf * 16 + g * 4 + r;  // C layout: row=(lane>>4)*4+r
                    float h = acc[nf][cf][r] + bj;
                    h = (h - mm) * (gm * iv) + bb;
                    h = h >= 0.f ? h : 0.1f * h;
                    sH[nrow * DO + j] = f2bf(h);
                }
            }
        }
        __syncthreads();
        ushort* Hout = (ushort*)OutP;
        constexpr int UPR = DO / 8;    // 16B-units per row
#pragma unroll
        for (int it = 0; it < (32 * UPR) / 256; ++it) {
            int u = it * 256 + t;
            int nd = u / UPR, c = u % UPR;
            if (node0 + nd < n)
                *(uint4*)(Hout + (size_t)(node0 + nd) * DO + c * 8) =
                    *(uint4*)&sH[nd * DO + c * 8];
        }
    } else {
        // DO==64, CF==1: bias + row L2-normalize, f32 out
        float* Outf = (float*)OutP;
        int j = wv * 16 + rowl;
        float bj = bias[j];
        float h[2][4];
#pragma unroll
        for (int nf = 0; nf < 2; ++nf)
#pragma unroll
            for (int r = 0; r < 4; ++r) {
                h[nf][r] = acc[nf][0][r] + bj;
                float s = h[nf][r] * h[nf][r];
                s += __shfl_xor(s, 1);   // reduce over 16 cols of this jc
                s += __shfl_xor(s, 2);
                s += __shfl_xor(s, 4);
                s += __shfl_xor(s, 8);
                if (rowl == 0) atomicAdd(&ssrow[nf * 16 + g * 4 + r], s);
            }
        __syncthreads();
#pragma unroll
        for (int nf = 0; nf < 2; ++nf)
#pragma unroll
            for (int r = 0; r < 4; ++r) {
                int nrow = nf * 16 + g * 4 + r;
                int node = node0 + nrow;
                if (node < n) {
                    float sc = 1.0f / fmaxf(sqrtf(ssrow[nrow]), 1e-12f);
                    Outf[(size_t)node * 64 + j] = h[nf][r] * sc;
                }
            }
    }
}

// ---------------- launch ----------------

extern "C" void kernel_launch(void* const* d_in, const int* in_sizes, int n_in,
                              void* d_out, int out_size, void* d_ws, size_t ws_size,
                              hipStream_t stream) {
    const float* x = (const float*)d_in[0];
    const int* ei = (const int*)d_in[1];  // int32 staging
    const float* ew = (const float*)d_in[2];
    const float* W1l = (const float*)d_in[3];
    const float* b1 = (const float*)d_in[4];
    const float* W1r = (const float*)d_in[5];
    const float* W2l = (const float*)d_in[6];
    const float* b2 = (const float*)d_in[7];
    const float* W2r = (const float*)d_in[8];
    const float* W3l = (const float*)d_in[9];
    const float* b3 = (const float*)d_in[10];
    const float* W3r = (const float*)d_in[11];
    const float* bn1_g = (const float*)d_in[12];
    const float* bn1_b = (const float*)d_in[13];
    const float* bn1_m = (const float*)d_in[14];
    const float* bn1_v = (const float*)d_in[15];
    const float* bn2_g = (const float*)d_in[16];
    const float* bn2_b = (const float*)d_in[17];
    const float* bn2_m = (const float*)d_in[18];
    const float* bn2_v = (const float*)d_in[19];

    const int N = in_sizes[0] / IN_D;  // 50000
    const int E = in_sizes[2];         // 800000
    float* out = (float*)d_out;

    char* p = (char*)d_ws;
    auto alloc = [&](size_t bytes) -> void* {
        void* r = (void*)p;
        p += (bytes + 255) & ~(size_t)255;
        return r;
    };
    int* deg = (int*)alloc((size_t)N * 4);
    int* rowptr = (int*)alloc((size_t)(N + 1) * 4);
    int* cursor = (int*)alloc((size_t)N * 4);
    float* invcnt = (float*)alloc((size_t)N * 4);
    int* bsum = (int*)alloc(256 * 4);
    int2* csr = (int2*)alloc((size_t)E * 8);
    ushort* xb = (ushort*)alloc((size_t)N * 128 * 2);   // bf16 x
    ushort* Mb = (ushort*)alloc((size_t)N * 128 * 2);   // bf16 agg mean
    ushort* H1b = (ushort*)alloc((size_t)N * 128 * 2);  // bf16 layer outs
    ushort* H2b = (ushort*)alloc((size_t)N * 128 * 2);
    ushort* WB1 = (ushort*)alloc(32768 * 2);
    ushort* WB2 = (ushort*)alloc(32768 * 2);
    ushort* WB3 = (ushort*)alloc(16384 * 2);

    const int NB = (N + 255) / 256;
    const int EB = (E + 255) / 256;
    const int AGG_B = (N + 3) / 4;      // 4 waves (nodes) per 256-thread block
    const int GEMM_B = (N + 31) / 32;   // 32 nodes per block
    const int CVT_B = (N * 128 / 4 + 255) / 256;

    // --- CSR build + weight pack + x conversion ---
    hipMemsetAsync(deg, 0, (size_t)N * 4, stream);
    k_hist<<<EB, 256, 0, stream>>>(ei, deg, E, N);
    k_prep<<<320, 256, 0, stream>>>(W1l, W1r, W2l, W2r, W3l, W3r, WB1, WB2, WB3);
    k_cvt<<<CVT_B, 256, 0, stream>>>((const float4*)x, (ushort4*)xb, N * 128 / 4);
    k_block_sum<<<NB, 256, 0, stream>>>(deg, bsum, N);
    k_scan_bsum<<<1, 256, 0, stream>>>(bsum, NB);
    k_scan_deg<<<NB, 256, 0, stream>>>(deg, bsum, rowptr, cursor, invcnt, N);
    k_fill<<<EB, 256, 0, stream>>>(ei, ew, cursor, csr, E, N);

    // --- layer 1 ---
    k_agg<<<AGG_B, 256, 0, stream>>>((const unsigned*)xb, rowptr, csr, invcnt,
                                     (unsigned*)Mb, N);
    k_gemm5<128, 1><<<GEMM_B, 256, 0, stream>>>(Mb, xb, WB1, b1, bn1_g, bn1_b, bn1_m,
                                                bn1_v, (void*)H1b, N);
    // --- layer 2 ---
    k_agg<<<AGG_B, 256, 0, stream>>>((const unsigned*)H1b, rowptr, csr, invcnt,
                                     (unsigned*)Mb, N);
    k_gemm5<128, 1><<<GEMM_B, 256, 0, stream>>>(Mb, H1b, WB2, b2, bn2_g, bn2_b, bn2_m,
                                                bn2_v, (void*)H2b, N);
    // --- layer 3 (+ fused L2 normalize, f32 out) ---
    k_agg<<<AGG_B, 256, 0, stream>>>((const unsigned*)H2b, rowptr, csr, invcnt,
                                     (unsigned*)Mb, N);
    k_gemm5<64, 0><<<GEMM_B, 256, 0, stream>>>(Mb, H2b, WB3, b3, nullptr, nullptr,
                                               nullptr, nullptr, (void*)out, N);
}